// Round 1
// 1284.595 us; speedup vs baseline: 1.0447x; 1.0447x over previous
//
#include <hip/hip_runtime.h>
#include <hip/hip_bf16.h>

// Problem constants (from reference)
#define NN   50000
#define EE   1600000
#define INC  128
#define HH   64
#define OUTC 40
#define ALPHA 0.8f
#define LN_EPS 1e-5f
#define NB_SCAN 196   // ceil(NN/256)
// h is stored pre-scaled by 2*log2(e) so tanh needs no per-edge multiply:
// tanh(x) = 1 - 2/(1 + 2^(KTANH*x))
#define KTANH 2.8853900817779268f

// ---------------------------------------------------------------------------
// Raw buffer load (CK-style declaration). Gather addressing moves to
// SALU (s_and on the wave-uniform edge value -> soffset) + constant
// per-lane voffset: ZERO VALU instructions per gather.
// ---------------------------------------------------------------------------
typedef int v4i_t __attribute__((ext_vector_type(4)));
__device__ float llvm_amdgcn_raw_buffer_load_fp32(v4i_t srsrc, int voffset,
                                                  int soffset, int glc_slc)
    __asm("llvm.amdgcn.raw.buffer.load.f32");

// ---------------------------------------------------------------------------
// Wave64 sum via fused v_add_f32_dpp (inline asm; 1 inst/stage guaranteed).
// 8 independent chains interleaved (also satisfies DPP wait-states).
// Total lands in lane 63.
// Stage 1 writes FRESH dests for s0..s3 (reads d0..d3 directly) so the
// d values survive for the final fma without v_mov copies.
// ---------------------------------------------------------------------------
#define DPP8(CTRL)                                                             \
    asm volatile(                                                              \
        "v_add_f32_dpp %0, %0, %0 " CTRL "\n\t"                                \
        "v_add_f32_dpp %1, %1, %1 " CTRL "\n\t"                                \
        "v_add_f32_dpp %2, %2, %2 " CTRL "\n\t"                                \
        "v_add_f32_dpp %3, %3, %3 " CTRL "\n\t"                                \
        "v_add_f32_dpp %4, %4, %4 " CTRL "\n\t"                                \
        "v_add_f32_dpp %5, %5, %5 " CTRL "\n\t"                                \
        "v_add_f32_dpp %6, %6, %6 " CTRL "\n\t"                                \
        "v_add_f32_dpp %7, %7, %7 " CTRL                                       \
        : "+v"(s0), "+v"(s1), "+v"(s2), "+v"(s3),                              \
          "+v"(s4), "+v"(s5), "+v"(s6), "+v"(s7))

#define DPP8_FIRST(CTRL)                                                       \
    asm volatile(                                                              \
        "v_add_f32_dpp %0, %8, %8 " CTRL "\n\t"                                \
        "v_add_f32_dpp %1, %9, %9 " CTRL "\n\t"                                \
        "v_add_f32_dpp %2, %10, %10 " CTRL "\n\t"                              \
        "v_add_f32_dpp %3, %11, %11 " CTRL "\n\t"                              \
        "v_add_f32_dpp %4, %4, %4 " CTRL "\n\t"                                \
        "v_add_f32_dpp %5, %5, %5 " CTRL "\n\t"                                \
        "v_add_f32_dpp %6, %6, %6 " CTRL "\n\t"                                \
        "v_add_f32_dpp %7, %7, %7 " CTRL                                       \
        : "=&v"(s0), "=&v"(s1), "=&v"(s2), "=&v"(s3),                          \
          "+v"(s4), "+v"(s5), "+v"(s6), "+v"(s7)                               \
        : "v"(d0), "v"(d1), "v"(d2), "v"(d3))

#define DPP_ALL6()                                                             \
    DPP8_FIRST("row_shr:1 row_mask:0xf bank_mask:0xf bound_ctrl:0");           \
    DPP8("row_shr:2 row_mask:0xf bank_mask:0xf bound_ctrl:0");                 \
    DPP8("row_shr:4 row_mask:0xf bank_mask:0xf bound_ctrl:0");                 \
    DPP8("row_shr:8 row_mask:0xf bank_mask:0xf bound_ctrl:0");                 \
    DPP8("row_bcast:15 row_mask:0xa bank_mask:0xf bound_ctrl:0");              \
    DPP8("row_bcast:31 row_mask:0xc bank_mask:0xf bound_ctrl:0")

__device__ __forceinline__ float rl63(float x) {
    return __int_as_float(__builtin_amdgcn_readlane(__float_as_int(x), 63));
}

// input already pre-scaled by KTANH: tanh = 1 - 2/(1 + 2^xs)
// xs->-inf: e->0, u->1, d->-1. xs->+inf: e->inf, u->0, d->+1. rcp(inf)=0 safe.
__device__ __forceinline__ float fast_tanh_pre(float xs) {
    float e = __builtin_amdgcn_exp2f(xs);
    float u = __builtin_amdgcn_rcpf(1.0f + e);
    return __builtin_fmaf(-2.0f, u, 1.0f);
}

// one quad (4 edges): returns sum_i rsig_i*(d_i-mu_i).
// GUARD=true applies the tail-validity mask (j0+i < nv).
// hn/hv pre-scaled by KTANH.
template <bool GUARD>
__device__ __forceinline__ float quad_contrib(float hn, float hv0, float hv1,
                                              float hv2, float hv3,
                                              int j0, int nv) {
    float d0 = fast_tanh_pre(hn - hv0);
    float d1 = fast_tanh_pre(hn - hv1);
    float d2 = fast_tanh_pre(hn - hv2);
    float d3 = fast_tanh_pre(hn - hv3);
    float s0, s1, s2, s3;
    float s4 = d0 * d0, s5 = d1 * d1, s6 = d2 * d2, s7 = d3 * d3;
    DPP_ALL6();
    float t10 = rl63(s0), t11 = rl63(s1), t12 = rl63(s2), t13 = rl63(s3);
    float t20 = rl63(s4), t21 = rl63(s5), t22 = rl63(s6), t23 = rl63(s7);

    float acc = 0.f, mu, var, rsig;
    // var+eps folded: v = fma(t2,1/64, fma(-mu,mu,eps)).
    // t2/64 - mu^2 >= 0 (Cauchy-Schwarz); fp error ~1e-7 << eps=1e-5,
    // so var >= ~9.9e-6 > 0 always: no clamp needed.
    mu  = t10 * 0.015625f;
    var = __builtin_fmaf(t20, 0.015625f, __builtin_fmaf(-mu, mu, LN_EPS));
    rsig = __frsqrt_rn(var);
    if (GUARD) rsig = (j0 + 0 < nv) ? rsig : 0.f;
    acc = __builtin_fmaf(rsig, d0 - mu, acc);

    mu  = t11 * 0.015625f;
    var = __builtin_fmaf(t21, 0.015625f, __builtin_fmaf(-mu, mu, LN_EPS));
    rsig = __frsqrt_rn(var);
    if (GUARD) rsig = (j0 + 1 < nv) ? rsig : 0.f;
    acc = __builtin_fmaf(rsig, d1 - mu, acc);

    mu  = t12 * 0.015625f;
    var = __builtin_fmaf(t22, 0.015625f, __builtin_fmaf(-mu, mu, LN_EPS));
    rsig = __frsqrt_rn(var);
    if (GUARD) rsig = (j0 + 2 < nv) ? rsig : 0.f;
    acc = __builtin_fmaf(rsig, d2 - mu, acc);

    mu  = t13 * 0.015625f;
    var = __builtin_fmaf(t23, 0.015625f, __builtin_fmaf(-mu, mu, LN_EPS));
    rsig = __frsqrt_rn(var);
    if (GUARD) rsig = (j0 + 3 < nv) ? rsig : 0.f;
    acc = __builtin_fmaf(rsig, d3 - mu, acc);
    return acc;
}

// ---------------------------------------------------------------------------
// CSR build, atomic-light (R10): count returns per-node rank; fill is
// atomic-free scattered stores (L2-absorbed).
// adj entry encoding (R12): byte-offset form  (other<<8) | (role<<31)
//   bits [23:8] = other node id * 256 = byte offset of its h row
//   bit 31      = role (1 if this incidence sees the node as col -> sign -1)
// ---------------------------------------------------------------------------
__global__ __launch_bounds__(256) void csr_count(const int* __restrict__ ei,
                                                 int* __restrict__ cnt,
                                                 unsigned short* __restrict__ rank16) {
    int i = blockIdx.x * 256 + threadIdx.x;
    if (i >= 2 * EE) return;
    int r = atomicAdd(&cnt[ei[i]], 1);
    rank16[i] = (unsigned short)r;
}

__global__ __launch_bounds__(256) void scanA(const int* __restrict__ cnt,
                                             int* __restrict__ offs,
                                             int* __restrict__ bsum) {
    __shared__ int tmp[256];
    int i = blockIdx.x * 256 + threadIdx.x;
    int v = (i < NN) ? cnt[i] : 0;
    tmp[threadIdx.x] = v;
    __syncthreads();
    int acc = v;
    for (int d = 1; d < 256; d <<= 1) {
        int t = (threadIdx.x >= d) ? tmp[threadIdx.x - d] : 0;
        __syncthreads();
        acc += t;
        tmp[threadIdx.x] = acc;
        __syncthreads();
    }
    if (i < NN) offs[i] = acc - v;
    if (threadIdx.x == 255) bsum[blockIdx.x] = acc;
}

__global__ __launch_bounds__(256) void scanB(int* __restrict__ bsum) {
    __shared__ int tmp[256];
    int v = (threadIdx.x < NB_SCAN) ? bsum[threadIdx.x] : 0;
    tmp[threadIdx.x] = v;
    __syncthreads();
    int acc = v;
    for (int d = 1; d < 256; d <<= 1) {
        int t = (threadIdx.x >= d) ? tmp[threadIdx.x - d] : 0;
        __syncthreads();
        acc += t;
        tmp[threadIdx.x] = acc;
        __syncthreads();
    }
    if (threadIdx.x < NB_SCAN) bsum[threadIdx.x] = acc - v;
}

__global__ __launch_bounds__(256) void scanC(int* __restrict__ offs,
                                             const int* __restrict__ bsum) {
    int i = blockIdx.x * 256 + threadIdx.x;
    if (i < NN) offs[i] += bsum[blockIdx.x];
}

__global__ __launch_bounds__(256) void csr_fill(const int* __restrict__ ei,
                                                const int* __restrict__ offs,
                                                const unsigned short* __restrict__ rank16,
                                                int* __restrict__ adj) {
    int i = blockIdx.x * 256 + threadIdx.x;
    if (i >= 2 * EE) return;
    int node  = ei[i];
    int role  = (i >= EE) ? 1 : 0;
    int other = role ? ei[i - EE] : ei[i + EE];
    adj[offs[node] + (int)rank16[i]] =
        (int)(((unsigned)other << 8) | ((unsigned)role << 31));
}

// ---------------------------------------------------------------------------
// G = W @ W^T  (64x64). One block.
// ---------------------------------------------------------------------------
__global__ __launch_bounds__(256) void make_G(const float* __restrict__ W,
                                              float* __restrict__ G) {
    __shared__ float Ws[64 * 64];
    for (int t = threadIdx.x; t < 64 * 64; t += 256) Ws[t] = W[t];
    __syncthreads();
    for (int t = threadIdx.x; t < 64 * 64; t += 256) {
        int i = t >> 6, j = t & 63;
        float acc = 0.f;
#pragma unroll 8
        for (int k = 0; k < 64; ++k) acc += Ws[i * 64 + k] * Ws[j * 64 + k];
        G[t] = acc;
    }
}

// ---------------------------------------------------------------------------
// extractor: xh = x@We^T + be ; h0 = KTANH*(xh@U^T + bU) ; xU = (xh@U^T+bU)/nf
// (h buffers carry the KTANH pre-scale; xU stays unscaled)
// ---------------------------------------------------------------------------
__global__ __launch_bounds__(256) void extractor(
        const float* __restrict__ x, const float* __restrict__ nf,
        const float* __restrict__ We, const float* __restrict__ be,
        const float* __restrict__ U,  const float* __restrict__ bU,
        float* __restrict__ xh, float* __restrict__ xU, float* __restrict__ h0) {
    __shared__ float WeT[INC * HH];
    __shared__ float UT[HH * HH];
    __shared__ float beS[HH], bUS[HH];
    __shared__ float xs[4][INC];
    __shared__ float xhs[4][HH];

    for (int t = threadIdx.x; t < INC * HH; t += 256) {
        int j = t >> 7, k = t & 127;
        WeT[k * 64 + j] = We[t];
    }
    for (int t = threadIdx.x; t < HH * HH; t += 256) {
        int j = t >> 6, k = t & 63;
        UT[k * 64 + j] = U[t];
    }
    if (threadIdx.x < 64) { beS[threadIdx.x] = be[threadIdx.x]; bUS[threadIdx.x] = bU[threadIdx.x]; }
    __syncthreads();

    int lane = threadIdx.x & 63;
    int wv   = threadIdx.x >> 6;

    for (int n0 = blockIdx.x * 4; n0 < NN; n0 += gridDim.x * 4) {
        int n = n0 + wv;
        bool valid = n < NN;
        if (valid) {
            xs[wv][lane]      = x[(size_t)n * INC + lane];
            xs[wv][lane + 64] = x[(size_t)n * INC + lane + 64];
        }
        __syncthreads();
        float acc = beS[lane];
        if (valid) {
#pragma unroll 8
            for (int k = 0; k < INC; ++k) acc += xs[wv][k] * WeT[k * 64 + lane];
            xh[n * 64 + lane] = acc;
            xhs[wv][lane] = acc;
        }
        __syncthreads();
        if (valid) {
            float acc2 = bUS[lane];
#pragma unroll 8
            for (int k = 0; k < HH; ++k) acc2 += xhs[wv][k] * UT[k * 64 + lane];
            h0[n * 64 + lane] = KTANH * acc2;
            xU[n * 64 + lane] = acc2 / nf[n];
        }
        __syncthreads();
    }
}

// ---------------------------------------------------------------------------
// fused step v7 (R12): buffer-load gathers with SALU soffset addressing,
// pre-scaled h, clamp-free LN, mov-free DPP stage 1. No atomics.
// ---------------------------------------------------------------------------
__global__ __launch_bounds__(256) void fused_step(
        const int* __restrict__ adj, const int* __restrict__ offs,
        const int* __restrict__ cnt,
        const float* __restrict__ hcur, float* __restrict__ hnxt,
        const float* __restrict__ nf, const float* __restrict__ gamma,
        const float* __restrict__ beta, const float* __restrict__ Gm,
        const float* __restrict__ xU,
        float* __restrict__ y, float* __restrict__ s, int first, int last) {
    __shared__ float Gs[64 * 64];
    for (int t = threadIdx.x; t < 64 * 64; t += 256) Gs[t] = Gm[t];
    __syncthreads();

    const int lane = threadIdx.x & 63, wv = threadIdx.x >> 6;
    const float g = gamma[lane], b = beta[lane];

    // SRSRC for hcur: num_records = NN*64*4 bytes exactly covers the array.
    v4i_t hsr;
    {
        unsigned long long up = (unsigned long long)(uintptr_t)hcur;
        hsr.x = (int)(unsigned)(up & 0xffffffffull);
        hsr.y = (int)(unsigned)(up >> 32);
        hsr.z = NN * HH * 4;
        hsr.w = 0x00020000;
    }
    const int lane4 = lane << 2;
    // adj value e: bits[23:8] = row byte-offset, bit31 = role.
    // soffset (wave-uniform, SALU s_and) + voffset lane4 -> 0 VALU per gather.
#define GATH(e) llvm_amdgcn_raw_buffer_load_fp32(hsr, lane4, (e) & 0x00ffff00, 0)

    for (int n = blockIdx.x * 4 + wv; n < NN; n += gridDim.x * 4) {
        const int base = __builtin_amdgcn_readfirstlane(offs[n]);
        const int deg  = __builtin_amdgcn_readfirstlane(cnt[n]);
        const float hn = hcur[(size_t)n * 64 + lane];
        float accM = 0.f;
        int sigma = 0;

        // ---- full 64-edge chunks: clamp-free, literal lane indices
        const int nfull = deg >> 6;
        for (int c = 0; c < nfull; ++c) {
            const int ev = adj[base + (c << 6) + lane];
            sigma += 64 - 2 * (int)__builtin_popcountll(__ballot(ev < 0));

            float hv0, hv1, hv2, hv3;
            {
                int e0 = __builtin_amdgcn_readlane(ev, 0);
                int e1 = __builtin_amdgcn_readlane(ev, 1);
                int e2 = __builtin_amdgcn_readlane(ev, 2);
                int e3 = __builtin_amdgcn_readlane(ev, 3);
                hv0 = GATH(e0);
                hv1 = GATH(e1);
                hv2 = GATH(e2);
                hv3 = GATH(e3);
            }
#pragma unroll
            for (int q = 0; q < 16; ++q) {
                const int j0 = q << 2;
                // wraparound prefetch: at q=15 re-loads edges 0..3 (discarded)
                int e0 = __builtin_amdgcn_readlane(ev, (j0 + 4) & 63);
                int e1 = __builtin_amdgcn_readlane(ev, (j0 + 5) & 63);
                int e2 = __builtin_amdgcn_readlane(ev, (j0 + 6) & 63);
                int e3 = __builtin_amdgcn_readlane(ev, (j0 + 7) & 63);
                float n0 = GATH(e0);
                float n1 = GATH(e1);
                float n2 = GATH(e2);
                float n3 = GATH(e3);

                accM += quad_contrib<false>(hn, hv0, hv1, hv2, hv3, 0, 64);

                hv0 = n0; hv1 = n1; hv2 = n2; hv3 = n3;
            }
        }

        // ---- remainder chunk (deg & 63 edges), guarded
        const int rem = deg & 63;
        if (rem) {
            const int rbase = base + (nfull << 6);
            int li = lane < rem ? lane : rem - 1;
            int ev = adj[rbase + li];
            unsigned long long bal = __ballot(ev < 0);
            unsigned long long msk = (1ull << rem) - 1ull;
            sigma += rem - 2 * (int)__builtin_popcountll(bal & msk);

            float hv0, hv1, hv2, hv3;
            {
                int j1 = 1 < rem ? 1 : rem - 1;
                int j2 = 2 < rem ? 2 : rem - 1;
                int j3 = 3 < rem ? 3 : rem - 1;
                int e0 = __builtin_amdgcn_readlane(ev, 0);
                int e1 = __builtin_amdgcn_readlane(ev, j1);
                int e2 = __builtin_amdgcn_readlane(ev, j2);
                int e3 = __builtin_amdgcn_readlane(ev, j3);
                hv0 = GATH(e0);
                hv1 = GATH(e1);
                hv2 = GATH(e2);
                hv3 = GATH(e3);
            }
            const int quads = (rem + 3) >> 2;
            for (int q = 0; q < quads; ++q) {
                const int j0 = q << 2;
                int ja = j0 + 4; ja = ja < rem ? ja : rem - 1;
                int jb = j0 + 5; jb = jb < rem ? jb : rem - 1;
                int jc = j0 + 6; jc = jc < rem ? jc : rem - 1;
                int jd = j0 + 7; jd = jd < rem ? jd : rem - 1;
                int e0 = __builtin_amdgcn_readlane(ev, ja);
                int e1 = __builtin_amdgcn_readlane(ev, jb);
                int e2 = __builtin_amdgcn_readlane(ev, jc);
                int e3 = __builtin_amdgcn_readlane(ev, jd);
                float n0 = GATH(e0);
                float n1 = GATH(e1);
                float n2 = GATH(e2);
                float n3 = GATH(e3);

                accM += quad_contrib<true>(hn, hv0, hv1, hv2, hv3, j0, rem);

                hv0 = n0; hv1 = n1; hv2 = n2; hv3 = n3;
            }
        }
#undef GATH

        const float nfn = nf[n];
        const float av  = nfn * __builtin_fmaf(g, accM, b * (float)sigma);

        // p[lane] = sum_k av(lane k) * G[k][lane] via readlane broadcast
        float p = 0.f;
        const int avi = __float_as_int(av);
#pragma unroll
        for (int k = 0; k < 64; ++k) {
            float ak = __int_as_float(__builtin_amdgcn_readlane(avi, k));
            p = __builtin_fmaf(ak, Gs[k * 64 + lane], p);
        }

        float yprev = 0.f, sprev = 0.f;
        if (!first) {
            yprev = y[n * 64 + lane];
            sprev = s[n * 64 + lane];
        }
        const float yv = -ALPHA * p + (1.0f - ALPHA) * yprev;
        y[n * 64 + lane] = yv;
        s[n * 64 + lane] = (1.0f - ALPHA) * sprev + av;
        // hnxt carries the KTANH pre-scale (consumed only inside tanh diffs)
        if (!last) hnxt[n * 64 + lane] = KTANH * (nfn * (yv + xU[n * 64 + lane]));
    }
}

// ---------------------------------------------------------------------------
// final: z = -alpha*(s@W) ; zf = nf*z + xh ; out = zf@Wlast^T + blast
// ---------------------------------------------------------------------------
__global__ __launch_bounds__(256) void final_out(
        const float* __restrict__ s, const float* __restrict__ xh,
        const float* __restrict__ nf, const float* __restrict__ W,
        const float* __restrict__ Wlast, const float* __restrict__ blast,
        float* __restrict__ out) {
    __shared__ float Ws[64 * 64];
    __shared__ float WlT[64 * OUTC];
    __shared__ float blS[OUTC];
    __shared__ float ss[4][64];
    __shared__ float zfs[4][64];
    for (int t = threadIdx.x; t < 64 * 64; t += 256) Ws[t] = W[t];
    for (int t = threadIdx.x; t < OUTC * 64; t += 256) {
        int o = t >> 6, j = t & 63;
        WlT[j * OUTC + o] = Wlast[t];
    }
    if (threadIdx.x < OUTC) blS[threadIdx.x] = blast[threadIdx.x];
    __syncthreads();
    int lane = threadIdx.x & 63, wv = threadIdx.x >> 6;
    for (int n0 = blockIdx.x * 4; n0 < NN; n0 += gridDim.x * 4) {
        int n = n0 + wv;
        if (n < NN) ss[wv][lane] = s[n * 64 + lane];
        __syncthreads();
        if (n < NN) {
            float z = 0.f;
#pragma unroll 8
            for (int k = 0; k < 64; ++k) z += ss[wv][k] * Ws[k * 64 + lane];
            z *= -ALPHA;
            zfs[wv][lane] = nf[n] * z + xh[n * 64 + lane];
        }
        __syncthreads();
        if (n < NN && lane < OUTC) {
            float acc = blS[lane];
#pragma unroll 8
            for (int j = 0; j < 64; ++j) acc += zfs[wv][j] * WlT[j * OUTC + lane];
            out[n * OUTC + lane] = acc;
        }
        __syncthreads();
    }
}

// ---------------------------------------------------------------------------
extern "C" void kernel_launch(void* const* d_in, const int* in_sizes, int n_in,
                              void* d_out, int out_size, void* d_ws, size_t ws_size,
                              hipStream_t stream) {
    const float* x     = (const float*)d_in[0];
    const int*   ei    = (const int*)  d_in[1];
    const float* nf    = (const float*)d_in[2];
    const float* We    = (const float*)d_in[3];
    const float* be    = (const float*)d_in[4];
    const float* W     = (const float*)d_in[5];
    const float* U     = (const float*)d_in[6];
    const float* bU    = (const float*)d_in[7];
    const float* gamma = (const float*)d_in[8];
    const float* beta  = (const float*)d_in[9];
    const float* Wlast = (const float*)d_in[10];
    const float* blast = (const float*)d_in[11];
    float* out = (float*)d_out;

    char* ws = (char*)d_ws;
    size_t off = 0;
    const size_t NH = (size_t)NN * HH * sizeof(float);
    int*   adj    = (int*)(ws + off);            off += (size_t)2 * EE * sizeof(int);
    unsigned short* rank16 = (unsigned short*)(ws + off);
                                                 off += (size_t)2 * EE * sizeof(unsigned short);
    int*   offs   = (int*)(ws + off);            off += (size_t)NN * sizeof(int);
    int*   cnt    = (int*)(ws + off);            off += (size_t)NN * sizeof(int);
    int*   bsum   = (int*)(ws + off);            off += 256 * sizeof(int);
    float* xh     = (float*)(ws + off);          off += NH;
    float* xU     = (float*)(ws + off);          off += NH;
    float* h0     = (float*)(ws + off);          off += NH;
    float* h1     = (float*)(ws + off);          off += NH;
    float* y      = (float*)(ws + off);          off += NH;
    float* s      = (float*)(ws + off);          off += NH;
    float* G      = (float*)(ws + off);          off += (size_t)HH * HH * sizeof(float);

    hipMemsetAsync(cnt, 0, (size_t)NN * sizeof(int), stream);
    // y/s zero-init folded into fused_step (first=1)

    // CSR build (once per launch): atomic count (+rank capture), scan,
    // atomic-free fill.
    csr_count<<<(2 * EE + 255) / 256, 256, 0, stream>>>(ei, cnt, rank16);
    scanA<<<NB_SCAN, 256, 0, stream>>>(cnt, offs, bsum);
    scanB<<<1, 256, 0, stream>>>(bsum);
    scanC<<<NB_SCAN, 256, 0, stream>>>(offs, bsum);
    csr_fill<<<(2 * EE + 255) / 256, 256, 0, stream>>>(ei, offs, rank16, adj);

    make_G<<<1, 256, 0, stream>>>(W, G);
    extractor<<<2048, 256, 0, stream>>>(x, nf, We, be, U, bU, xh, xU, h0);

    float* hc = h0;
    float* hn = h1;
    for (int t = 0; t < 4; ++t) {
        fused_step<<<2048, 256, 0, stream>>>(adj, offs, cnt, hc, hn, nf,
                                             gamma, beta, G, xU, y, s,
                                             t == 0, t == 3);
        float* tmp = hc; hc = hn; hn = tmp;
    }
    final_out<<<2048, 256, 0, stream>>>(s, xh, nf, W, Wlast, blast, out);
}